// Round 6
// baseline (397.937 us; speedup 1.0000x reference)
//
#include <hip/hip_runtime.h>
#include <stdint.h>

typedef unsigned short u16;
typedef unsigned int u32;
typedef float f32x4 __attribute__((ext_vector_type(4)));
typedef short short8 __attribute__((ext_vector_type(8)));

#define NBAT 32
#define NSEQ 4096
#define ND 256
#define NSLOT 7
#define NCHUNK 64

// ---------------- helpers ----------------
__device__ __forceinline__ u32 bf16rne(float f){
  u32 u = __float_as_uint(f);
  u = u + 0x7FFFu + ((u >> 16) & 1u);
  return u >> 16;
}
__device__ __forceinline__ u32 packbf(float a, float b){
  return (bf16rne(a) & 0xFFFFu) | (bf16rne(b) << 16);
}
__device__ __forceinline__ float bflo(u32 u){ return __uint_as_float(u << 16); }
__device__ __forceinline__ float bfhi(u32 u){ return __uint_as_float(u & 0xFFFF0000u); }

__device__ __forceinline__ void gld16(void* lds, const void* g){
  __builtin_amdgcn_global_load_lds(
      (const __attribute__((address_space(1))) u32*)g,
      (__attribute__((address_space(3))) u32*)lds, 16, 0, 0);
}

// ---------------- prep: bf16 weight copies, bias concat, slots init ----------------
__global__ __launch_bounds__(256) void k_prep(
    const float* __restrict__ wk, const float* __restrict__ wv,
    const float* __restrict__ bk, const float* __restrict__ bv,
    const float* __restrict__ mu, const float* __restrict__ sig,
    const float* __restrict__ noise,
    const float* __restrict__ w_ih, const float* __restrict__ b_ih,
    const float* __restrict__ w_hh, const float* __restrict__ b_hh,
    const float* __restrict__ w1, const float* __restrict__ w2,
    const float* __restrict__ wq,
    u16* __restrict__ Wkv, float* __restrict__ biaskv, float* __restrict__ slots,
    u16* __restrict__ Wg, u16* __restrict__ w1b, u16* __restrict__ w2b,
    u16* __restrict__ wqb, float* __restrict__ bg){
  const int bid = blockIdx.x, t = threadIdx.x;
  if (bid < 512){
    const float* src = (bid < 256) ? (wk + (size_t)bid*256) : (wv + (size_t)(bid-256)*256);
    Wkv[(size_t)bid*256 + t] = (u16)bf16rne(src[t]);
  } else if (bid == 512){
    biaskv[t] = bk[t];
    biaskv[256 + t] = bv[t];
  } else if (bid < 737){
    int r = bid - 513; // 0..223
    float sp = logf(1.f + expf(sig[t]));   // softplus
    slots[(size_t)r*256 + t] = mu[t] + sp * noise[(size_t)r*256 + t];
  } else if (bid < 1761){
    // Wg[1024][512]: rows 0-511 = [wih|whh]; 512-767 = [wih_n|0]; 768-1023 = [0|whh_n]
    int j = bid - 737;
    u16 a, b;
    if (j < 512){ a = (u16)bf16rne(w_ih[(size_t)j*256 + t]); b = (u16)bf16rne(w_hh[(size_t)j*256 + t]); }
    else if (j < 768){ a = (u16)bf16rne(w_ih[(size_t)j*256 + t]); b = 0; }
    else { a = 0; b = (u16)bf16rne(w_hh[(size_t)(j-256)*256 + t]); }
    Wg[(size_t)j*512 + t] = a;
    Wg[(size_t)j*512 + 256 + t] = b;
  } else if (bid < 2273){
    int j = bid - 1761; // 0..511
    w1b[(size_t)j*256 + t] = (u16)bf16rne(w1[(size_t)j*256 + t]);
  } else if (bid < 2529){
    int j = bid - 2273; // 0..255
    w2b[(size_t)j*512 + t]       = (u16)bf16rne(w2[(size_t)j*512 + t]);
    w2b[(size_t)j*512 + 256 + t] = (u16)bf16rne(w2[(size_t)j*512 + 256 + t]);
  } else if (bid < 2785){
    int j = bid - 2529; // 0..255
    wqb[(size_t)j*256 + t] = (u16)bf16rne(wq[(size_t)j*256 + t]);
  } else {
#pragma unroll
    for (int ii = 0; ii < 4; ++ii){
      int j = ii*256 + t;
      float v;
      if (j < 512) v = b_ih[j] + b_hh[j];
      else if (j < 768) v = b_ih[j];
      else v = b_hh[j - 256];
      bg[j] = v;
    }
  }
}

// ---------------- K1: LayerNorm(inputs) -> x bf16, one wave per row ----------------
__global__ __launch_bounds__(256) void k_ln_in(
    const float* __restrict__ x, const float* __restrict__ g, const float* __restrict__ b,
    u16* __restrict__ xo){
  const int row = blockIdx.x*4 + (threadIdx.x >> 6);
  const int lane = threadIdx.x & 63;
  const f32x4 v = *(const f32x4*)(x + (size_t)row*ND + lane*4);
  float s  = v[0]+v[1]+v[2]+v[3];
  float s2 = v[0]*v[0]+v[1]*v[1]+v[2]*v[2]+v[3]*v[3];
#pragma unroll
  for (int m = 1; m < 64; m <<= 1){ s += __shfl_xor(s, m); s2 += __shfl_xor(s2, m); }
  const float mean = s * (1.f/256.f);
  const float var  = s2 * (1.f/256.f) - mean*mean;
  const float rstd = rsqrtf(var + 1e-5f);
  const f32x4 gg = *(const f32x4*)(g + lane*4);
  const f32x4 bb = *(const f32x4*)(b + lane*4);
  float y0 = (v[0]-mean)*rstd*gg[0] + bb[0];
  float y1 = (v[1]-mean)*rstd*gg[1] + bb[1];
  float y2 = (v[2]-mean)*rstd*gg[2] + bb[2];
  float y3 = (v[3]-mean)*rstd*gg[3] + bb[3];
  uint2 o; o.x = packbf(y0, y1); o.y = packbf(y2, y3);
  *(uint2*)(xo + (size_t)row*ND + lane*4) = o;
}

// ---------------- K2: kv = x @ Wkv^T + bias ----------------
// W (256 KB total) is L2-resident -> fragments load DIRECT global->VGPR, issued
// before the A-stage barrier (latency hidden). Only A goes through LDS:
// 16 KB single-buffer -> high block residency, half the barrier-drained bytes.
__global__ __launch_bounds__(256) void k_gemm_kv(
    const u16* __restrict__ X, const u16* __restrict__ W,
    const float* __restrict__ biaskv, u16* __restrict__ kv){
  __shared__ __align__(16) u16 At[128*64];     // 16 KB
  const int bid = blockIdx.x;                  // 0..4095
  const int swz = ((bid & 7) << 9) + (bid >> 3);
  const int mb = swz >> 2, nb = swz & 3;
  const int tid = threadIdx.x, w = tid >> 6, lane = tid & 63;
  const int wm = w >> 1, wn = w & 1;
  const int l15 = lane & 15, g = lane >> 4;
  f32x4 acc[4][4];
#pragma unroll
  for (int a = 0; a < 4; ++a)
#pragma unroll
    for (int c = 0; c < 4; ++c) acc[a][c] = (f32x4){0.f,0.f,0.f,0.f};

  const int cl = lane & 7;
  const u16* wbase = W + ((size_t)(nb*128 + wn*64 + l15))*256;
  for (int kt = 0; kt < 4; ++kt){
    // W fragments: direct from global (L2 hit), independent of the barrier below
    short8 wf[2][4];
#pragma unroll
    for (int kk = 0; kk < 2; ++kk)
#pragma unroll
      for (int wi = 0; wi < 4; ++wi)
        wf[kk][wi] = *(const short8*)(wbase + (size_t)wi*16*256 + kt*64 + (kk*4 + g)*8);
    __syncthreads();     // prior compute done before LDS overwrite
#pragma unroll
    for (int i = 0; i < 4; ++i){
      int R = w*32 + i*8 + (lane >> 3);
      int c = cl ^ (R & 7);
      gld16(&At[(w*32 + i*8)*64], X + ((size_t)(mb*128 + R))*256 + kt*64 + c*8);
    }
    __syncthreads();     // A tile ready (compiler drains vmcnt before barrier)
#pragma unroll
    for (int kk = 0; kk < 2; ++kk){
      short8 xf[4];
#pragma unroll
      for (int xi = 0; xi < 4; ++xi){
        int r = wm*64 + xi*16 + l15;
        int ch = (kk*4 + g) ^ (r & 7);
        xf[xi] = *(const short8*)&At[r*64 + ch*8];
      }
#pragma unroll
      for (int xi = 0; xi < 4; ++xi)
#pragma unroll
        for (int wi = 0; wi < 4; ++wi)
          acc[xi][wi] = __builtin_amdgcn_mfma_f32_16x16x32_bf16(wf[kk][wi], xf[xi], acc[xi][wi], 0, 0, 0);
    }
  }
  f32x4 bias[4];
#pragma unroll
  for (int wi = 0; wi < 4; ++wi)
    bias[wi] = *(const f32x4*)(biaskv + nb*128 + wn*64 + wi*16 + g*4);
#pragma unroll
  for (int xi = 0; xi < 4; ++xi){
    size_t m = (size_t)mb*128 + wm*64 + xi*16 + l15;
    u16* dst = kv + m*512 + nb*128 + wn*64 + g*4;
#pragma unroll
    for (int wi = 0; wi < 4; ++wi){
      f32x4 c = acc[xi][wi];
      uint2 o;
      o.x = packbf(c[0] + bias[wi][0], c[1] + bias[wi][1]);
      o.y = packbf(c[2] + bias[wi][2], c[3] + bias[wi][3]);
      *(uint2*)(dst + wi*16) = o;
    }
  }
}

// ---------------- small-GEMM (MFMA, 128x128, dbuf 2-phase): out = A @ W^T + bias ----
// MODE 0: gates, f32 out ld=1024
// MODE 1: mlp1, relu -> bf16 out ld=512
// MODE 2: mlp2, + snew + bias -> slots f32 ld=256 (rows<224), optional out_slots copy
// MODE 3: qproj, (acc+bias)*log2(e)/16 -> BF16 out ld=256
template<int MODE>
__global__ __launch_bounds__(256) void k_gemm_s(
    const u16* __restrict__ A, const u16* __restrict__ W,
    const float* __restrict__ bias, int nkt,
    float* __restrict__ outf, u16* __restrict__ outb,
    const float* __restrict__ snew, float* __restrict__ out2, int last){
  __shared__ __align__(16) u16 At[2][128*64];
  __shared__ __align__(16) u16 Bt[2][128*64];
  const int nb = blockIdx.x, mb = blockIdx.y;
  const int tid = threadIdx.x, w = tid >> 6, lane = tid & 63;
  const int wm = w >> 1, wn = w & 1;
  const size_t K = (size_t)nkt * 64;
  f32x4 acc[4][4];
#pragma unroll
  for (int a = 0; a < 4; ++a)
#pragma unroll
    for (int c = 0; c < 4; ++c) acc[a][c] = (f32x4){0.f,0.f,0.f,0.f};

  const int cl = lane & 7;
#define STAGE_S(buf, kt)                                                         \
  {                                                                              \
    _Pragma("unroll")                                                            \
    for (int i = 0; i < 4; ++i){                                                 \
      int R = w*32 + i*8 + (lane >> 3);                                          \
      int c = cl ^ (R & 7);                                                      \
      gld16(&At[buf][(w*32 + i*8)*64], A + ((size_t)(mb*128 + R))*K + (kt)*64 + c*8); \
      gld16(&Bt[buf][(w*32 + i*8)*64], W + ((size_t)(nb*128 + R))*K + (kt)*64 + c*8); \
    }                                                                            \
  }
  STAGE_S(0, 0);
  __syncthreads();
  for (int kt = 0; kt < nkt; ++kt){
    const int cur = kt & 1;
    if (kt < nkt - 1) STAGE_S(cur ^ 1, kt + 1);
#pragma unroll
    for (int kk = 0; kk < 2; ++kk){
      short8 xf[4], wf[4];
#pragma unroll
      for (int xi = 0; xi < 4; ++xi){
        int r = wm*64 + xi*16 + (lane & 15);
        int ch = (kk*4 + (lane >> 4)) ^ (r & 7);
        xf[xi] = *(const short8*)&At[cur][r*64 + ch*8];
      }
#pragma unroll
      for (int wi = 0; wi < 4; ++wi){
        int r = wn*64 + wi*16 + (lane & 15);
        int ch = (kk*4 + (lane >> 4)) ^ (r & 7);
        wf[wi] = *(const short8*)&Bt[cur][r*64 + ch*8];
      }
#pragma unroll
      for (int xi = 0; xi < 4; ++xi)
#pragma unroll
        for (int wi = 0; wi < 4; ++wi)
          acc[xi][wi] = __builtin_amdgcn_mfma_f32_16x16x32_bf16(wf[wi], xf[xi], acc[xi][wi], 0, 0, 0);
    }
    __syncthreads();
  }
#undef STAGE_S
  const int LDO = (MODE == 0) ? 1024 : ((MODE == 1) ? 512 : 256);
  f32x4 b4[4];
#pragma unroll
  for (int wi = 0; wi < 4; ++wi)
    b4[wi] = *(const f32x4*)(bias + nb*128 + wn*64 + wi*16 + (lane >> 4)*4);
#pragma unroll
  for (int xi = 0; xi < 4; ++xi){
    const int m = mb*128 + wm*64 + xi*16 + (lane & 15);
    const int colb = nb*128 + wn*64 + (lane >> 4)*4;
#pragma unroll
    for (int wi = 0; wi < 4; ++wi){
      const int col = colb + wi*16;
      f32x4 c = acc[xi][wi] + b4[wi];
      if (MODE == 0){
        *(f32x4*)(outf + (size_t)m*LDO + col) = c;
      } else if (MODE == 1){
        uint2 o;
        o.x = packbf(fmaxf(c[0],0.f), fmaxf(c[1],0.f));
        o.y = packbf(fmaxf(c[2],0.f), fmaxf(c[3],0.f));
        *(uint2*)(outb + (size_t)m*LDO + col) = o;
      } else if (MODE == 2){
        if (m < 224){
          const f32x4 s4 = *(const f32x4*)(snew + (size_t)m*256 + col);
          f32x4 o = c + s4;
          *(f32x4*)(outf + (size_t)m*LDO + col) = o;
          if (last) *(f32x4*)(out2 + (size_t)m*LDO + col) = o;
        }
      } else { // MODE 3: bf16 q, pre-scaled
        uint2 o;
        o.x = packbf(c[0]*0.09016844f, c[1]*0.09016844f);
        o.y = packbf(c[2]*0.09016844f, c[3]*0.09016844f);
        *(uint2*)(outb + (size_t)m*LDO + col) = o;
      }
    }
  }
}

// ---------------- K4: MFMA QK^T -> softmax(S) -> VALU PV; partials out ----------------
__global__ __launch_bounds__(256) void k_attn(
    const u16* __restrict__ kv, const u16* __restrict__ qb,
    float* __restrict__ attn_out, float* __restrict__ pacc, float* __restrict__ pw){
  __shared__ __align__(16) float accbuf[4][7][256];   // 28 KB
  __shared__ __align__(16) float p_lds[4][16][8];     // 2 KB
  __shared__ float wsum_lds[4][8];
  const int chunk = blockIdx.x, b = blockIdx.y;
  const int tid = threadIdx.x, w = tid >> 6, lane = tid & 63;
  const int l15 = lane & 15, g = lane >> 4, hi = lane >> 5;
  const size_t bbase = (size_t)b*NSEQ;
  const int nr0 = chunk*64 + w*16;   // wave's first row

  short8 qf[8];
  {
    const u16* qrow = qb + ((size_t)b*7 + l15)*256;
#pragma unroll
    for (int ks = 0; ks < 8; ++ks)
      qf[ks] = *(const short8*)(qrow + (ks*4 + g)*8);
  }
  f32x4 z = {0.f,0.f,0.f,0.f};
#pragma unroll
  for (int ks = 0; ks < 8; ++ks){
    const short8 kf = *(const short8*)(kv + (bbase + nr0 + l15)*512 + (ks*4 + g)*8);
    z = __builtin_amdgcn_mfma_f32_16x16x32_bf16(qf[ks], kf, z, 0, 0, 0);
  }
  float zz[4];
#pragma unroll
  for (int j = 0; j < 4; ++j){
    const int s = g*4 + j;
    zz[j] = (s < 7) ? z[j] : -3.0e38f;
  }
  float mx = fmaxf(fmaxf(zz[0], zz[1]), fmaxf(zz[2], zz[3]));
  mx = fmaxf(mx, __shfl_xor(mx, 16));
  float p[4], psum = 0.f;
#pragma unroll
  for (int j = 0; j < 4; ++j){ p[j] = exp2f(zz[j] - mx); psum += p[j]; }
  psum += __shfl_xor(psum, 16);
  const float rs = 1.f / psum;
#pragma unroll
  for (int j = 0; j < 4; ++j) p[j] = fmaf(p[j], rs, 1e-8f);
  float wloc[4] = {0.f,0.f,0.f,0.f};
  if (lane < 32){
    *(f32x4*)&p_lds[w][l15][g*4] = (f32x4){p[0], p[1], p[2], p[3]};
    const size_t arow = (bbase + nr0 + l15)*7;
#pragma unroll
    for (int j = 0; j < 4; ++j){
      const int s = g*4 + j;
      if (s < 7){ attn_out[arow + s] = p[j]; wloc[j] = p[j]; }
    }
  }
  __syncthreads();
  float acc[7][4];
#pragma unroll
  for (int s = 0; s < 7; ++s){ acc[s][0]=acc[s][1]=acc[s][2]=acc[s][3]=0.f; }
#pragma unroll
  for (int it = 0; it < 8; ++it){
    const int rm = it*2 + hi, ro = it*2 + (1 - hi);
    const uint2 va = *(const uint2*)(kv + (bbase + nr0 + rm)*512 + 256 + (size_t)lane*4);
    const uint2 vb = *(const uint2*)(kv + (bbase + nr0 + ro)*512 + 256 + (size_t)lane*4);
    const f32x4 pm0 = *(const f32x4*)&p_lds[w][rm][0];
    const f32x4 pm1 = *(const f32x4*)&p_lds[w][rm][4];
    const f32x4 po0 = *(const f32x4*)&p_lds[w][ro][0];
    const f32x4 po1 = *(const f32x4*)&p_lds[w][ro][4];
    const float pm[7] = {pm0[0],pm0[1],pm0[2],pm0[3],pm1[0],pm1[1],pm1[2]};
    const float po[7] = {po0[0],po0[1],po0[2],po0[3],po1[0],po1[1],po1[2]};
    const float vm0=bflo(va.x), vm1=bfhi(va.x), vm2=bflo(va.y), vm3=bfhi(va.y);
    const float vo0=bflo(vb.x), vo1=bfhi(vb.x), vo2=bflo(vb.y), vo3=bfhi(vb.y);
#pragma unroll
    for (int s = 0; s < 7; ++s){
      acc[s][0] = fmaf(pm[s], vm0, fmaf(po[s], vo0, acc[s][0]));
      acc[s][1] = fmaf(pm[s], vm1, fmaf(po[s], vo1, acc[s][1]));
      acc[s][2] = fmaf(pm[s], vm2, fmaf(po[s], vo2, acc[s][2]));
      acc[s][3] = fmaf(pm[s], vm3, fmaf(po[s], vo3, acc[s][3]));
    }
  }
#pragma unroll
  for (int m = 1; m < 16; m <<= 1){
#pragma unroll
    for (int j = 0; j < 4; ++j) wloc[j] += __shfl_xor(wloc[j], m);
  }
  if (lane < 32 && l15 == 0){
#pragma unroll
    for (int j = 0; j < 4; ++j) wsum_lds[w][g*4 + j] = wloc[j];
  }
  __syncthreads();
#pragma unroll
  for (int s = 0; s < 7; ++s)
    *(f32x4*)&accbuf[w][s][lane*4] = (f32x4){acc[s][0], acc[s][1], acc[s][2], acc[s][3]};
  __syncthreads();
#pragma unroll
  for (int s = 0; s < 7; ++s){
    float sum = accbuf[0][s][tid] + accbuf[1][s][tid] + accbuf[2][s][tid] + accbuf[3][s][tid];
    pacc[((size_t)chunk*NBAT + b)*(NSLOT*256) + s*256 + tid] = sum;
  }
  if (tid < 7)
    pw[((size_t)chunk*NBAT + b)*NSLOT + tid] =
        wsum_lds[0][tid] + wsum_lds[1][tid] + wsum_lds[2][tid] + wsum_lds[3][tid];
}

// ---------------- slotA: reduce pacc -> A2 = [bf16(updates) | bf16(slots_prev)] ----------------
__global__ __launch_bounds__(256) void k_slotA(
    const float* __restrict__ pacc, const float* __restrict__ pw,
    const float* __restrict__ slots, u16* __restrict__ A2, float* __restrict__ wsum){
  __shared__ float pwb[NCHUNK];
  const int r = blockIdx.x, t = threadIdx.x;
  if (r >= 224){
    A2[(size_t)r*512 + t] = 0;
    A2[(size_t)r*512 + 256 + t] = 0;
    return;
  }
  if (t < NCHUNK) pwb[t] = pw[(size_t)t*224 + r];
  float u = 0.f;
#pragma unroll 8
  for (int c = 0; c < NCHUNK; ++c) u += pacc[(size_t)c*57344 + (size_t)r*256 + t];
  __syncthreads();
  float wst = 0.f;
#pragma unroll
  for (int c = 0; c < NCHUNK; ++c) wst += pwb[c];
  if (t == 0) wsum[r] = wst;
  A2[(size_t)r*512 + t] = (u16)bf16rne(u / wst);
  A2[(size_t)r*512 + 256 + t] = (u16)bf16rne(slots[(size_t)r*256 + t]);
}

// ---------------- slotB: GRU elementwise + LN -> lnm bf16, snew f32 ----------------
__global__ __launch_bounds__(256) void k_slotB(
    const float* __restrict__ gates, const float* __restrict__ slots,
    const float* __restrict__ gm, const float* __restrict__ bm,
    float* __restrict__ snew, u16* __restrict__ lnm){
  __shared__ float red[8];
  const int r = blockIdx.x, t = threadIdx.x;
  if (r >= 224){ lnm[(size_t)r*256 + t] = 0; return; }
  const float g0  = gates[(size_t)r*1024 + t];
  const float g1  = gates[(size_t)r*1024 + 256 + t];
  const float gin = gates[(size_t)r*1024 + 512 + t];
  const float ghn = gates[(size_t)r*1024 + 768 + t];
  const float spv = slots[(size_t)r*256 + t];
  const float rr = 1.f/(1.f + __expf(-g0));
  const float zz = 1.f/(1.f + __expf(-g1));
  float xx = gin + rr*ghn;
  xx = fminf(fmaxf(xx, -15.f), 15.f);
  const float e2 = __expf(2.f*xx);
  const float nn = (e2 - 1.f)/(e2 + 1.f);
  const float sp = (1.f - zz)*nn + zz*spv;
  snew[(size_t)r*256 + t] = sp;
  float s = sp, s2 = sp*sp;
#pragma unroll
  for (int m = 1; m < 64; m <<= 1){ s += __shfl_xor(s, m); s2 += __shfl_xor(s2, m); }
  if ((t & 63) == 0){ red[t >> 6] = s; red[4 + (t >> 6)] = s2; }
  __syncthreads();
  const float ssum = red[0]+red[1]+red[2]+red[3];
  const float qsum = red[4]+red[5]+red[6]+red[7];
  const float mean = ssum*(1.f/256.f);
  const float var  = qsum*(1.f/256.f) - mean*mean;
  const float rstd = rsqrtf(var + 1e-5f);
  lnm[(size_t)r*256 + t] = (u16)bf16rne((sp - mean)*rstd*gm[t] + bm[t]);
}

// ---------------- lnq: LN(slots) -> lnq bf16 ----------------
__global__ __launch_bounds__(256) void k_lnq(
    const float* __restrict__ slots, const float* __restrict__ g, const float* __restrict__ b,
    u16* __restrict__ lnq){
  __shared__ float red[8];
  const int r = blockIdx.x, t = threadIdx.x;
  if (r >= 224){ lnq[(size_t)r*256 + t] = 0; return; }
  const float x = slots[(size_t)r*256 + t];
  float s = x, s2 = x*x;
#pragma unroll
  for (int m = 1; m < 64; m <<= 1){ s += __shfl_xor(s, m); s2 += __shfl_xor(s2, m); }
  if ((t & 63) == 0){ red[t >> 6] = s; red[4 + (t >> 6)] = s2; }
  __syncthreads();
  const float ssum = red[0]+red[1]+red[2]+red[3];
  const float qsum = red[4]+red[5]+red[6]+red[7];
  const float mean = ssum*(1.f/256.f);
  const float var  = qsum*(1.f/256.f) - mean*mean;
  const float rstd = rsqrtf(var + 1e-5f);
  lnq[(size_t)r*256 + t] = (u16)bf16rne((x - mean)*rstd*g[t] + b[t]);
}

// ---------------- K6: attn /= sum over n ----------------
__global__ __launch_bounds__(256) void k_norm(
    float* __restrict__ attn, const float* __restrict__ wsum_tot){
  size_t i = (size_t)blockIdx.x*256 + threadIdx.x;
  int s = (int)(i % 7);
  int b = (int)(i / (NSEQ*7));
  attn[i] = attn[i] / wsum_tot[b*7 + s];
}

// ---------------- launch ----------------
extern "C" void kernel_launch(void* const* d_in, const int* in_sizes, int n_in,
                              void* d_out, int out_size, void* d_ws, size_t ws_size,
                              hipStream_t stream){
  (void)in_sizes; (void)n_in; (void)out_size; (void)ws_size;
  const float* inputs  = (const float*)d_in[0];
  const float* noise   = (const float*)d_in[1];
  const float* ln_in_g = (const float*)d_in[2];
  const float* ln_in_b = (const float*)d_in[3];
  const float* ln_sl_g = (const float*)d_in[4];
  const float* ln_sl_b = (const float*)d_in[5];
  const float* ln_ml_g = (const float*)d_in[6];
  const float* ln_ml_b = (const float*)d_in[7];
  const float* mu      = (const float*)d_in[8];
  const float* sig     = (const float*)d_in[9];
  const float* wq      = (const float*)d_in[10];
  const float* bq      = (const float*)d_in[11];
  const float* wk      = (const float*)d_in[12];
  const float* bk      = (const float*)d_in[13];
  const float* wv      = (const float*)d_in[14];
  const float* bv      = (const float*)d_in[15];
  const float* w_ih    = (const float*)d_in[16];
  const float* b_ih    = (const float*)d_in[17];
  const float* w_hh    = (const float*)d_in[18];
  const float* b_hh    = (const float*)d_in[19];
  const float* w1      = (const float*)d_in[20];
  const float* b1      = (const float*)d_in[21];
  const float* w2      = (const float*)d_in[22];
  const float* b2      = (const float*)d_in[23];

  char* ws = (char*)d_ws;
  u16*   x_bf   = (u16*)(ws);                         // 67108864
  u16*   kv     = (u16*)(ws + 67108864);              // 134217728 -> ends 201326592
  char*  paccch = ws + 201326592;                     // 14680064 (pacc; transients alias below)
  float* pacc   = (float*)paccch;
  u16*   Wkv    = (u16*)(ws + 216006656);             // 262144
  u16*   qeffb  = (u16*)(ws + 216268800);             // 131072 (256 rows bf16)
  float* slots  = (float*)(ws + 216530944);           // 229376
  float* pw     = (float*)(ws + 216760320);           // 57344
  float* biaskv = (float*)(ws + 216817664);           // 2048
  float* wsum   = (float*)(ws + 216819712);           // 1024
  u16*   A2     = (u16*)(ws + 216820736);             // 262144
  u16*   Wg     = (u16*)(ws + 217082880);             // 1048576
  u16*   w1b    = (u16*)(ws + 218131456);             // 262144
  u16*   w2b    = (u16*)(ws + 218393600);             // 262144
  u16*   wqb    = (u16*)(ws + 218655744);             // 131072
  float* bg     = (float*)(ws + 218786816);           // 4096

  // transients aliased into pacc region (dead between slotA and next attn)
  float* gates  = (float*)(paccch);                   // 1048576
  u16*   hb     = (u16*)(paccch + 1048576);           // 262144
  u16*   lnm    = (u16*)(paccch + 1310720);           // 131072
  u16*   lnq    = (u16*)(paccch + 1441792);           // 131072
  float* snew   = (float*)(paccch + 1572864);         // 229376

  float* out_slots = (float*)d_out;
  float* attn = (float*)d_out + 57344;

  k_prep<<<2786, 256, 0, stream>>>(wk, wv, bk, bv, mu, sig, noise,
                                   w_ih, b_ih, w_hh, b_hh, w1, w2, wq,
                                   Wkv, biaskv, slots, Wg, w1b, w2b, wqb, bg);
  k_ln_in<<<32768, 256, 0, stream>>>(inputs, ln_in_g, ln_in_b, x_bf);
  k_gemm_kv<<<4096, 256, 0, stream>>>(x_bf, Wkv, biaskv, kv);
  for (int i = 0; i < 3; ++i){
    const int last = (i == 2) ? 1 : 0;
    k_lnq<<<256, 256, 0, stream>>>(slots, ln_sl_g, ln_sl_b, lnq);
    k_gemm_s<3><<<dim3(2, 2), 256, 0, stream>>>(lnq, wqb, bq, 4, nullptr, qeffb, nullptr, nullptr, 0);
    k_attn<<<dim3(NCHUNK, 32), 256, 0, stream>>>(kv, qeffb, attn, pacc, pw);
    k_slotA<<<256, 256, 0, stream>>>(pacc, pw, slots, A2, wsum);
    k_gemm_s<0><<<dim3(8, 2), 256, 0, stream>>>(A2, Wg, bg, 8, gates, nullptr, nullptr, nullptr, 0);
    k_slotB<<<256, 256, 0, stream>>>(gates, slots, ln_ml_g, ln_ml_b, snew, lnm);
    k_gemm_s<1><<<dim3(4, 2), 256, 0, stream>>>(lnm, w1b, b1, 4, nullptr, hb, nullptr, nullptr, 0);
    k_gemm_s<2><<<dim3(2, 2), 256, 0, stream>>>(hb, w2b, b2, 8, slots, nullptr, snew, out_slots, last);
  }
  k_norm<<<3584, 256, 0, stream>>>(attn, wsum);
}

// Round 7
// 369.072 us; speedup vs baseline: 1.0782x; 1.0782x over previous
//
#include <hip/hip_runtime.h>
#include <stdint.h>

typedef unsigned short u16;
typedef unsigned int u32;
typedef float f32x4 __attribute__((ext_vector_type(4)));
typedef short short8 __attribute__((ext_vector_type(8)));

#define NBAT 32
#define NSEQ 4096
#define ND 256
#define NSLOT 7
#define NCHUNK 64

// ---------------- helpers ----------------
__device__ __forceinline__ u32 bf16rne(float f){
  u32 u = __float_as_uint(f);
  u = u + 0x7FFFu + ((u >> 16) & 1u);
  return u >> 16;
}
__device__ __forceinline__ u32 packbf(float a, float b){
  return (bf16rne(a) & 0xFFFFu) | (bf16rne(b) << 16);
}
__device__ __forceinline__ float bflo(u32 u){ return __uint_as_float(u << 16); }
__device__ __forceinline__ float bfhi(u32 u){ return __uint_as_float(u & 0xFFFF0000u); }

__device__ __forceinline__ void gld16(void* lds, const void* g){
  __builtin_amdgcn_global_load_lds(
      (const __attribute__((address_space(1))) u32*)g,
      (__attribute__((address_space(3))) u32*)lds, 16, 0, 0);
}

// ---------------- prep: bf16 weight copies, bias concat, slots init ----------------
__global__ __launch_bounds__(256) void k_prep(
    const float* __restrict__ wk, const float* __restrict__ wv,
    const float* __restrict__ bk, const float* __restrict__ bv,
    const float* __restrict__ mu, const float* __restrict__ sig,
    const float* __restrict__ noise,
    const float* __restrict__ w_ih, const float* __restrict__ b_ih,
    const float* __restrict__ w_hh, const float* __restrict__ b_hh,
    const float* __restrict__ w1, const float* __restrict__ w2,
    const float* __restrict__ wq,
    u16* __restrict__ Wkv, float* __restrict__ biaskv, float* __restrict__ slots,
    u16* __restrict__ Wg, u16* __restrict__ w1b, u16* __restrict__ w2b,
    u16* __restrict__ wqb, float* __restrict__ bg){
  const int bid = blockIdx.x, t = threadIdx.x;
  if (bid < 512){
    const float* src = (bid < 256) ? (wk + (size_t)bid*256) : (wv + (size_t)(bid-256)*256);
    Wkv[(size_t)bid*256 + t] = (u16)bf16rne(src[t]);
  } else if (bid == 512){
    biaskv[t] = bk[t];
    biaskv[256 + t] = bv[t];
  } else if (bid < 737){
    int r = bid - 513; // 0..223
    float sp = logf(1.f + expf(sig[t]));   // softplus
    slots[(size_t)r*256 + t] = mu[t] + sp * noise[(size_t)r*256 + t];
  } else if (bid < 1761){
    // Wg[1024][512]: rows 0-511 = [wih|whh]; 512-767 = [wih_n|0]; 768-1023 = [0|whh_n]
    int j = bid - 737;
    u16 a, b;
    if (j < 512){ a = (u16)bf16rne(w_ih[(size_t)j*256 + t]); b = (u16)bf16rne(w_hh[(size_t)j*256 + t]); }
    else if (j < 768){ a = (u16)bf16rne(w_ih[(size_t)j*256 + t]); b = 0; }
    else { a = 0; b = (u16)bf16rne(w_hh[(size_t)(j-256)*256 + t]); }
    Wg[(size_t)j*512 + t] = a;
    Wg[(size_t)j*512 + 256 + t] = b;
  } else if (bid < 2273){
    int j = bid - 1761; // 0..511
    w1b[(size_t)j*256 + t] = (u16)bf16rne(w1[(size_t)j*256 + t]);
  } else if (bid < 2529){
    int j = bid - 2273; // 0..255
    w2b[(size_t)j*512 + t]       = (u16)bf16rne(w2[(size_t)j*512 + t]);
    w2b[(size_t)j*512 + 256 + t] = (u16)bf16rne(w2[(size_t)j*512 + 256 + t]);
  } else if (bid < 2785){
    int j = bid - 2529; // 0..255
    wqb[(size_t)j*256 + t] = (u16)bf16rne(wq[(size_t)j*256 + t]);
  } else {
#pragma unroll
    for (int ii = 0; ii < 4; ++ii){
      int j = ii*256 + t;
      float v;
      if (j < 512) v = b_ih[j] + b_hh[j];
      else if (j < 768) v = b_ih[j];
      else v = b_hh[j - 256];
      bg[j] = v;
    }
  }
}

// ---------------- K1: LayerNorm(inputs) -> x bf16, one wave per row ----------------
__global__ __launch_bounds__(256) void k_ln_in(
    const float* __restrict__ x, const float* __restrict__ g, const float* __restrict__ b,
    u16* __restrict__ xo){
  const int row = blockIdx.x*4 + (threadIdx.x >> 6);
  const int lane = threadIdx.x & 63;
  const f32x4 v = *(const f32x4*)(x + (size_t)row*ND + lane*4);
  float s  = v[0]+v[1]+v[2]+v[3];
  float s2 = v[0]*v[0]+v[1]*v[1]+v[2]*v[2]+v[3]*v[3];
#pragma unroll
  for (int m = 1; m < 64; m <<= 1){ s += __shfl_xor(s, m); s2 += __shfl_xor(s2, m); }
  const float mean = s * (1.f/256.f);
  const float var  = s2 * (1.f/256.f) - mean*mean;
  const float rstd = rsqrtf(var + 1e-5f);
  const f32x4 gg = *(const f32x4*)(g + lane*4);
  const f32x4 bb = *(const f32x4*)(b + lane*4);
  float y0 = (v[0]-mean)*rstd*gg[0] + bb[0];
  float y1 = (v[1]-mean)*rstd*gg[1] + bb[1];
  float y2 = (v[2]-mean)*rstd*gg[2] + bb[2];
  float y3 = (v[3]-mean)*rstd*gg[3] + bb[3];
  uint2 o; o.x = packbf(y0, y1); o.y = packbf(y2, y3);
  *(uint2*)(xo + (size_t)row*ND + lane*4) = o;
}

// ---------------- K2: kv = x @ Wkv^T + bias (MFMA bf16, 128x128, R4 structure, XCD swz) ----
// R4 structure restored: both tiles via gld16 into 32KB single buffers, 2 barriers/kt.
// Proven 75-78us; dbuf (R5) and W-direct (R6) both regressed it.
__global__ __launch_bounds__(256) void k_gemm_kv(
    const u16* __restrict__ X, const u16* __restrict__ W,
    const float* __restrict__ biaskv, u16* __restrict__ kv){
  __shared__ __align__(16) u16 At[128*64];
  __shared__ __align__(16) u16 Bt[128*64];
  const int bid = blockIdx.x;                 // 0..4095
  const int swz = ((bid & 7) << 9) + (bid >> 3);
  const int mb = swz >> 2, nb = swz & 3;
  const int tid = threadIdx.x, w = tid >> 6, lane = tid & 63;
  const int wm = w >> 1, wn = w & 1;
  f32x4 acc[4][4];
#pragma unroll
  for (int a = 0; a < 4; ++a)
#pragma unroll
    for (int c = 0; c < 4; ++c) acc[a][c] = (f32x4){0.f,0.f,0.f,0.f};

  const int cl = lane & 7;
  for (int kt = 0; kt < 4; ++kt){
#pragma unroll
    for (int i = 0; i < 4; ++i){
      int R = w*32 + i*8 + (lane >> 3);
      int c = cl ^ (R & 7);
      gld16(&At[(w*32 + i*8)*64], X + ((size_t)(mb*128 + R))*256 + kt*64 + c*8);
      gld16(&Bt[(w*32 + i*8)*64], W + ((size_t)(nb*128 + R))*256 + kt*64 + c*8);
    }
    __syncthreads();
#pragma unroll
    for (int kk = 0; kk < 2; ++kk){
      short8 xf[4], wf[4];
#pragma unroll
      for (int xi = 0; xi < 4; ++xi){
        int r = wm*64 + xi*16 + (lane & 15);
        int ch = (kk*4 + (lane >> 4)) ^ (r & 7);
        xf[xi] = *(const short8*)&At[r*64 + ch*8];
      }
#pragma unroll
      for (int wi = 0; wi < 4; ++wi){
        int r = wn*64 + wi*16 + (lane & 15);
        int ch = (kk*4 + (lane >> 4)) ^ (r & 7);
        wf[wi] = *(const short8*)&Bt[r*64 + ch*8];
      }
#pragma unroll
      for (int xi = 0; xi < 4; ++xi)
#pragma unroll
        for (int wi = 0; wi < 4; ++wi)
          acc[xi][wi] = __builtin_amdgcn_mfma_f32_16x16x32_bf16(wf[wi], xf[xi], acc[xi][wi], 0, 0, 0);
    }
    __syncthreads();
  }
  f32x4 bias[4];
#pragma unroll
  for (int wi = 0; wi < 4; ++wi)
    bias[wi] = *(const f32x4*)(biaskv + nb*128 + wn*64 + wi*16 + (lane >> 4)*4);
#pragma unroll
  for (int xi = 0; xi < 4; ++xi){
    size_t m = (size_t)mb*128 + wm*64 + xi*16 + (lane & 15);
    u16* dst = kv + m*512 + nb*128 + wn*64 + (lane >> 4)*4;
#pragma unroll
    for (int wi = 0; wi < 4; ++wi){
      f32x4 c = acc[xi][wi];
      uint2 o;
      o.x = packbf(c[0] + bias[wi][0], c[1] + bias[wi][1]);
      o.y = packbf(c[2] + bias[wi][2], c[3] + bias[wi][3]);
      *(uint2*)(dst + wi*16) = o;
    }
  }
}

// ---------------- small-GEMM (MFMA, 128x128, dbuf 2-phase): out = A @ W^T + bias ----
// MODE 0: gates, f32 out ld=1024
// MODE 1: mlp1, relu -> bf16 out ld=512
// MODE 2: mlp2, + snew + bias -> slots f32 ld=256 (rows<224), optional out_slots copy
template<int MODE>
__global__ __launch_bounds__(256) void k_gemm_s(
    const u16* __restrict__ A, const u16* __restrict__ W,
    const float* __restrict__ bias, int nkt,
    float* __restrict__ outf, u16* __restrict__ outb,
    const float* __restrict__ snew, float* __restrict__ out2, int last){
  __shared__ __align__(16) u16 At[2][128*64];
  __shared__ __align__(16) u16 Bt[2][128*64];
  const int nb = blockIdx.x, mb = blockIdx.y;
  const int tid = threadIdx.x, w = tid >> 6, lane = tid & 63;
  const int wm = w >> 1, wn = w & 1;
  const size_t K = (size_t)nkt * 64;
  f32x4 acc[4][4];
#pragma unroll
  for (int a = 0; a < 4; ++a)
#pragma unroll
    for (int c = 0; c < 4; ++c) acc[a][c] = (f32x4){0.f,0.f,0.f,0.f};

  const int cl = lane & 7;
#define STAGE_S(buf, kt)                                                         \
  {                                                                              \
    _Pragma("unroll")                                                            \
    for (int i = 0; i < 4; ++i){                                                 \
      int R = w*32 + i*8 + (lane >> 3);                                          \
      int c = cl ^ (R & 7);                                                      \
      gld16(&At[buf][(w*32 + i*8)*64], A + ((size_t)(mb*128 + R))*K + (kt)*64 + c*8); \
      gld16(&Bt[buf][(w*32 + i*8)*64], W + ((size_t)(nb*128 + R))*K + (kt)*64 + c*8); \
    }                                                                            \
  }
  STAGE_S(0, 0);
  __syncthreads();
  for (int kt = 0; kt < nkt; ++kt){
    const int cur = kt & 1;
    if (kt < nkt - 1) STAGE_S(cur ^ 1, kt + 1);
#pragma unroll
    for (int kk = 0; kk < 2; ++kk){
      short8 xf[4], wf[4];
#pragma unroll
      for (int xi = 0; xi < 4; ++xi){
        int r = wm*64 + xi*16 + (lane & 15);
        int ch = (kk*4 + (lane >> 4)) ^ (r & 7);
        xf[xi] = *(const short8*)&At[cur][r*64 + ch*8];
      }
#pragma unroll
      for (int wi = 0; wi < 4; ++wi){
        int r = wn*64 + wi*16 + (lane & 15);
        int ch = (kk*4 + (lane >> 4)) ^ (r & 7);
        wf[wi] = *(const short8*)&Bt[cur][r*64 + ch*8];
      }
#pragma unroll
      for (int xi = 0; xi < 4; ++xi)
#pragma unroll
        for (int wi = 0; wi < 4; ++wi)
          acc[xi][wi] = __builtin_amdgcn_mfma_f32_16x16x32_bf16(wf[wi], xf[xi], acc[xi][wi], 0, 0, 0);
    }
    __syncthreads();
  }
#undef STAGE_S
  const int LDO = (MODE == 0) ? 1024 : ((MODE == 1) ? 512 : 256);
  f32x4 b4[4];
#pragma unroll
  for (int wi = 0; wi < 4; ++wi)
    b4[wi] = *(const f32x4*)(bias + nb*128 + wn*64 + wi*16 + (lane >> 4)*4);
#pragma unroll
  for (int xi = 0; xi < 4; ++xi){
    const int m = mb*128 + wm*64 + xi*16 + (lane & 15);
    const int colb = nb*128 + wn*64 + (lane >> 4)*4;
#pragma unroll
    for (int wi = 0; wi < 4; ++wi){
      const int col = colb + wi*16;
      f32x4 c = acc[xi][wi] + b4[wi];
      if (MODE == 0){
        *(f32x4*)(outf + (size_t)m*LDO + col) = c;
      } else if (MODE == 1){
        uint2 o;
        o.x = packbf(fmaxf(c[0],0.f), fmaxf(c[1],0.f));
        o.y = packbf(fmaxf(c[2],0.f), fmaxf(c[3],0.f));
        *(uint2*)(outb + (size_t)m*LDO + col) = o;
      } else if (MODE == 2){
        if (m < 224){
          const f32x4 s4 = *(const f32x4*)(snew + (size_t)m*256 + col);
          f32x4 o = c + s4;
          *(f32x4*)(outf + (size_t)m*LDO + col) = o;
          if (last) *(f32x4*)(out2 + (size_t)m*LDO + col) = o;
        }
      }
    }
  }
}

// ---------------- k_q: LN(slots) + qproj fused, one block per (b,s) row ----------------
// wave-cooperative GEMV, 8-way interleaved shuffle-reduce chains; wqb bf16 L2-resident.
__global__ __launch_bounds__(256) void k_q(
    const float* __restrict__ slots, const float* __restrict__ g, const float* __restrict__ b,
    const u16* __restrict__ wqb, const float* __restrict__ bq, u16* __restrict__ qeffb){
  __shared__ float lnv[256];
  __shared__ float red[8];
  const int r = blockIdx.x, t = threadIdx.x, w = t >> 6, lane = t & 63;
  const float x = slots[(size_t)r*256 + t];
  float s = x, s2 = x*x;
#pragma unroll
  for (int m = 1; m < 64; m <<= 1){ s += __shfl_xor(s, m); s2 += __shfl_xor(s2, m); }
  if ((t & 63) == 0){ red[t >> 6] = s; red[4 + (t >> 6)] = s2; }
  __syncthreads();
  const float ssum = red[0]+red[1]+red[2]+red[3];
  const float qsum = red[4]+red[5]+red[6]+red[7];
  const float mean = ssum*(1.f/256.f);
  const float var  = qsum*(1.f/256.f) - mean*mean;
  const float rstd = rsqrtf(var + 1e-5f);
  lnv[t] = (x - mean)*rstd*g[t] + b[t];
  __syncthreads();
  const f32x4 l4 = *(const f32x4*)&lnv[lane*4];
  for (int jj = 0; jj < 64; jj += 8){
    float sv[8];
#pragma unroll
    for (int u8 = 0; u8 < 8; ++u8){
      const int j = w*64 + jj + u8;
      const uint2 wr = *(const uint2*)(wqb + (size_t)j*256 + lane*4);
      float d = l4[0]*bflo(wr.x);
      d = fmaf(l4[1], bfhi(wr.x), d);
      d = fmaf(l4[2], bflo(wr.y), d);
      d = fmaf(l4[3], bfhi(wr.y), d);
#pragma unroll
      for (int m = 1; m < 64; m <<= 1) d += __shfl_xor(d, m);
      sv[u8] = d;
    }
#pragma unroll
    for (int u8 = 0; u8 < 8; ++u8){
      const int j = w*64 + jj + u8;
      if (lane == u8)
        qeffb[(size_t)r*256 + j] = (u16)bf16rne((sv[u8] + bq[j]) * 0.09016844f);
    }
  }
}

// ---------------- K4: MFMA QK^T -> softmax(S) -> VALU PV; partials out ----------------
__global__ __launch_bounds__(256) void k_attn(
    const u16* __restrict__ kv, const u16* __restrict__ qb,
    float* __restrict__ attn_out, float* __restrict__ pacc, float* __restrict__ pw){
  __shared__ __align__(16) float accbuf[4][7][256];   // 28 KB
  __shared__ __align__(16) float p_lds[4][16][8];     // 2 KB
  __shared__ float wsum_lds[4][8];
  const int chunk = blockIdx.x, b = blockIdx.y;
  const int tid = threadIdx.x, w = tid >> 6, lane = tid & 63;
  const int l15 = lane & 15, g = lane >> 4, hi = lane >> 5;
  const size_t bbase = (size_t)b*NSEQ;
  const int nr0 = chunk*64 + w*16;   // wave's first row

  short8 qf[8];
  {
    const u16* qrow = qb + ((size_t)b*7 + l15)*256;
#pragma unroll
    for (int ks = 0; ks < 8; ++ks)
      qf[ks] = *(const short8*)(qrow + (ks*4 + g)*8);
  }
  f32x4 z = {0.f,0.f,0.f,0.f};
#pragma unroll
  for (int ks = 0; ks < 8; ++ks){
    const short8 kf = *(const short8*)(kv + (bbase + nr0 + l15)*512 + (ks*4 + g)*8);
    z = __builtin_amdgcn_mfma_f32_16x16x32_bf16(qf[ks], kf, z, 0, 0, 0);
  }
  float zz[4];
#pragma unroll
  for (int j = 0; j < 4; ++j){
    const int s = g*4 + j;
    zz[j] = (s < 7) ? z[j] : -3.0e38f;
  }
  float mx = fmaxf(fmaxf(zz[0], zz[1]), fmaxf(zz[2], zz[3]));
  mx = fmaxf(mx, __shfl_xor(mx, 16));
  float p[4], psum = 0.f;
#pragma unroll
  for (int j = 0; j < 4; ++j){ p[j] = exp2f(zz[j] - mx); psum += p[j]; }
  psum += __shfl_xor(psum, 16);
  const float rs = 1.f / psum;
#pragma unroll
  for (int j = 0; j < 4; ++j) p[j] = fmaf(p[j], rs, 1e-8f);
  float wloc[4] = {0.f,0.f,0.f,0.f};
  if (lane < 32){
    *(f32x4*)&p_lds[w][l15][g*4] = (f32x4){p[0], p[1], p[2], p[3]};
    const size_t arow = (bbase + nr0 + l15)*7;
#pragma unroll
    for (int j = 0; j < 4; ++j){
      const int s = g*4 + j;
      if (s < 7){ attn_out[arow + s] = p[j]; wloc[j] = p[j]; }
    }
  }
  __syncthreads();
  float acc[7][4];
#pragma unroll
  for (int s = 0; s < 7; ++s){ acc[s][0]=acc[s][1]=acc[s][2]=acc[s][3]=0.f; }
#pragma unroll
  for (int it = 0; it < 8; ++it){
    const int rm = it*2 + hi, ro = it*2 + (1 - hi);
    const uint2 va = *(const uint2*)(kv + (bbase + nr0 + rm)*512 + 256 + (size_t)lane*4);
    const uint2 vb = *(const uint2*)(kv + (bbase + nr0 + ro)*512 + 256 + (size_t)lane*4);
    const f32x4 pm0 = *(const f32x4*)&p_lds[w][rm][0];
    const f32x4 pm1 = *(const f32x4*)&p_lds[w][rm][4];
    const f32x4 po0 = *(const f32x4*)&p_lds[w][ro][0];
    const f32x4 po1 = *(const f32x4*)&p_lds[w][ro][4];
    const float pm[7] = {pm0[0],pm0[1],pm0[2],pm0[3],pm1[0],pm1[1],pm1[2]};
    const float po[7] = {po0[0],po0[1],po0[2],po0[3],po1[0],po1[1],po1[2]};
    const float vm0=bflo(va.x), vm1=bfhi(va.x), vm2=bflo(va.y), vm3=bfhi(va.y);
    const float vo0=bflo(vb.x), vo1=bfhi(vb.x), vo2=bflo(vb.y), vo3=bfhi(vb.y);
#pragma unroll
    for (int s = 0; s < 7; ++s){
      acc[s][0] = fmaf(pm[s], vm0, fmaf(po[s], vo0, acc[s][0]));
      acc[s][1] = fmaf(pm[s], vm1, fmaf(po[s], vo1, acc[s][1]));
      acc[s][2] = fmaf(pm[s], vm2, fmaf(po[s], vo2, acc[s][2]));
      acc[s][3] = fmaf(pm[s], vm3, fmaf(po[s], vo3, acc[s][3]));
    }
  }
#pragma unroll
  for (int m = 1; m < 16; m <<= 1){
#pragma unroll
    for (int j = 0; j < 4; ++j) wloc[j] += __shfl_xor(wloc[j], m);
  }
  if (lane < 32 && l15 == 0){
#pragma unroll
    for (int j = 0; j < 4; ++j) wsum_lds[w][g*4 + j] = wloc[j];
  }
  __syncthreads();
#pragma unroll
  for (int s = 0; s < 7; ++s)
    *(f32x4*)&accbuf[w][s][lane*4] = (f32x4){acc[s][0], acc[s][1], acc[s][2], acc[s][3]};
  __syncthreads();
#pragma unroll
  for (int s = 0; s < 7; ++s){
    float sum = accbuf[0][s][tid] + accbuf[1][s][tid] + accbuf[2][s][tid] + accbuf[3][s][tid];
    pacc[((size_t)chunk*NBAT + b)*(NSLOT*256) + s*256 + tid] = sum;
  }
  if (tid < 7)
    pw[((size_t)chunk*NBAT + b)*NSLOT + tid] =
        wsum_lds[0][tid] + wsum_lds[1][tid] + wsum_lds[2][tid] + wsum_lds[3][tid];
}

// ---------------- slotA: reduce pacc -> A2 = [bf16(updates) | bf16(slots_prev)] ----------------
__global__ __launch_bounds__(256) void k_slotA(
    const float* __restrict__ pacc, const float* __restrict__ pw,
    const float* __restrict__ slots, u16* __restrict__ A2, float* __restrict__ wsum){
  __shared__ float pwb[NCHUNK];
  const int r = blockIdx.x, t = threadIdx.x;
  if (r >= 224){
    A2[(size_t)r*512 + t] = 0;
    A2[(size_t)r*512 + 256 + t] = 0;
    return;
  }
  if (t < NCHUNK) pwb[t] = pw[(size_t)t*224 + r];
  float u = 0.f;
#pragma unroll 8
  for (int c = 0; c < NCHUNK; ++c) u += pacc[(size_t)c*57344 + (size_t)r*256 + t];
  __syncthreads();
  float wst = 0.f;
#pragma unroll
  for (int c = 0; c < NCHUNK; ++c) wst += pwb[c];
  if (t == 0) wsum[r] = wst;
  A2[(size_t)r*512 + t] = (u16)bf16rne(u / wst);
  A2[(size_t)r*512 + 256 + t] = (u16)bf16rne(slots[(size_t)r*256 + t]);
}

// ---------------- slotB: GRU elementwise + LN -> lnm bf16, snew f32 ----------------
__global__ __launch_bounds__(256) void k_slotB(
    const float* __restrict__ gates, const float* __restrict__ slots,
    const float* __restrict__ gm, const float* __restrict__ bm,
    float* __restrict__ snew, u16* __restrict__ lnm){
  __shared__ float red[8];
  const int r = blockIdx.x, t = threadIdx.x;
  if (r >= 224){ lnm[(size_t)r*256 + t] = 0; return; }
  const float g0  = gates[(size_t)r*1024 + t];
  const float g1  = gates[(size_t)r*1024 + 256 + t];
  const float gin = gates[(size_t)r*1024 + 512 + t];
  const float ghn = gates[(size_t)r*1024 + 768 + t];
  const float spv = slots[(size_t)r*256 + t];
  const float rr = 1.f/(1.f + __expf(-g0));
  const float zz = 1.f/(1.f + __expf(-g1));
  float xx = gin + rr*ghn;
  xx = fminf(fmaxf(xx, -15.f), 15.f);
  const float e2 = __expf(2.f*xx);
  const float nn = (e2 - 1.f)/(e2 + 1.f);
  const float sp = (1.f - zz)*nn + zz*spv;
  snew[(size_t)r*256 + t] = sp;
  float s = sp, s2 = sp*sp;
#pragma unroll
  for (int m = 1; m < 64; m <<= 1){ s += __shfl_xor(s, m); s2 += __shfl_xor(s2, m); }
  if ((t & 63) == 0){ red[t >> 6] = s; red[4 + (t >> 6)] = s2; }
  __syncthreads();
  const float ssum = red[0]+red[1]+red[2]+red[3];
  const float qsum = red[4]+red[5]+red[6]+red[7];
  const float mean = ssum*(1.f/256.f);
  const float var  = qsum*(1.f/256.f) - mean*mean;
  const float rstd = rsqrtf(var + 1e-5f);
  lnm[(size_t)r*256 + t] = (u16)bf16rne((sp - mean)*rstd*gm[t] + bm[t]);
}

// ---------------- K6: attn /= sum over n ----------------
__global__ __launch_bounds__(256) void k_norm(
    float* __restrict__ attn, const float* __restrict__ wsum_tot){
  size_t i = (size_t)blockIdx.x*256 + threadIdx.x;
  int s = (int)(i % 7);
  int b = (int)(i / (NSEQ*7));
  attn[i] = attn[i] / wsum_tot[b*7 + s];
}

// ---------------- launch ----------------
extern "C" void kernel_launch(void* const* d_in, const int* in_sizes, int n_in,
                              void* d_out, int out_size, void* d_ws, size_t ws_size,
                              hipStream_t stream){
  (void)in_sizes; (void)n_in; (void)out_size; (void)ws_size;
  const float* inputs  = (const float*)d_in[0];
  const float* noise   = (const float*)d_in[1];
  const float* ln_in_g = (const float*)d_in[2];
  const float* ln_in_b = (const float*)d_in[3];
  const float* ln_sl_g = (const float*)d_in[4];
  const float* ln_sl_b = (const float*)d_in[5];
  const float* ln_ml_g = (const float*)d_in[6];
  const float* ln_ml_b = (const float*)d_in[7];
  const float* mu      = (const float*)d_in[8];
  const float* sig     = (const float*)d_in[9];
  const float* wq      = (const float*)d_in[10];
  const float* bq      = (const float*)d_in[11];
  const float* wk      = (const float*)d_in[12];
  const float* bk      = (const float*)d_in[13];
  const float* wv      = (const float*)d_in[14];
  const float* bv      = (const float*)d_in[15];
  const float* w_ih    = (const float*)d_in[16];
  const float* b_ih    = (const float*)d_in[17];
  const float* w_hh    = (const float*)d_in[18];
  const float* b_hh    = (const float*)d_in[19];
  const float* w1      = (const float*)d_in[20];
  const float* b1      = (const float*)d_in[21];
  const float* w2      = (const float*)d_in[22];
  const float* b2      = (const float*)d_in[23];

  char* ws = (char*)d_ws;
  u16*   x_bf   = (u16*)(ws);                         // 67108864
  u16*   kv     = (u16*)(ws + 67108864);              // 134217728 -> ends 201326592
  char*  paccch = ws + 201326592;                     // 14680064 (pacc; transients alias below)
  float* pacc   = (float*)paccch;
  u16*   Wkv    = (u16*)(ws + 216006656);             // 262144
  u16*   qeffb  = (u16*)(ws + 216268800);             // 131072 (256 rows bf16)
  float* slots  = (float*)(ws + 216530944);           // 229376
  float* pw     = (float*)(ws + 216760320);           // 57344
  float* biaskv = (float*)(ws + 216817664);           // 2048
  float* wsum   = (float*)(ws + 216819712);           // 1024
  u16*   A2     = (u16*)(ws + 216820736);             // 262144
  u16*   Wg     = (u16*)(ws + 217082880);             // 1048576
  u16*   w1b    = (u16*)(ws + 218131456);             // 262144
  u16*   w2b    = (u16*)(ws + 218393600);             // 262144
  u16*   wqb    = (u16*)(ws + 218655744);             // 131072
  float* bg     = (float*)(ws + 218786816);           // 4096

  // transients aliased into pacc region (dead between slotA and next attn)
  float* gates  = (float*)(paccch);                   // 1048576
  u16*   hb     = (u16*)(paccch + 1048576);           // 262144
  u16*   lnm    = (u16*)(paccch + 1310720);           // 131072
  float* snew   = (float*)(paccch + 1572864);         // 229376

  float* out_slots = (float*)d_out;
  float* attn = (float*)d_out + 57344;

  k_prep<<<2786, 256, 0, stream>>>(wk, wv, bk, bv, mu, sig, noise,
                                   w_ih, b_ih, w_hh, b_hh, w1, w2, wq,
                                   Wkv, biaskv, slots, Wg, w1b, w2b, wqb, bg);
  k_ln_in<<<32768, 256, 0, stream>>>(inputs, ln_in_g, ln_in_b, x_bf);
  k_gemm_kv<<<4096, 256, 0, stream>>>(x_bf, Wkv, biaskv, kv);
  for (int i = 0; i < 3; ++i){
    const int last = (i == 2) ? 1 : 0;
    k_q<<<224, 256, 0, stream>>>(slots, ln_sl_g, ln_sl_b, wqb, bq, qeffb);
    k_attn<<<dim3(NCHUNK, 32), 256, 0, stream>>>(kv, qeffb, attn, pacc, pw);
    k_slotA<<<256, 256, 0, stream>>>(pacc, pw, slots, A2, wsum);
    k_gemm_s<0><<<dim3(8, 2), 256, 0, stream>>>(A2, Wg, bg, 8, gates, nullptr, nullptr, nullptr, 0);
    k_slotB<<<256, 256, 0, stream>>>(gates, slots, ln_ml_g, ln_ml_b, snew, lnm);
    k_gemm_s<1><<<dim3(4, 2), 256, 0, stream>>>(lnm, w1b, b1, 4, nullptr, hb, nullptr, nullptr, 0);
    k_gemm_s<2><<<dim3(2, 2), 256, 0, stream>>>(hb, w2b, b2, 8, slots, nullptr, snew, out_slots, last);
  }
  k_norm<<<3584, 256, 0, stream>>>(attn, wsum);
}